// Round 2
// baseline (9656.589 us; speedup 1.0000x reference)
//
#include <hip/hip_runtime.h>
#include <math.h>

// ---------------------------------------------------------------------------
// RNN_63153199120819: MLP-in (6->256->256->256 ReLU) -> 2-layer LSTM (H=256,
// T=128, B=1024) -> MLP-out (256->256->256->6).
// Round 2: fp32 baseline, TIME-CHUNKED to fit workspace (~56 MB vs round-1's
// 264 MB which overran ws_size -> GPU memory fault).
// Per chunk of Tc=16 timesteps:
//   input MLP (s1 -> s2 -> Uc), 16 LSTM steps (hs_t overwrites u_t in Uc),
//   output MLP (Uc -> s1 -> s2 -> out).
// ---------------------------------------------------------------------------

namespace {
constexpr int kT   = 128;
constexpr int kB   = 1024;
constexpr int kLag = 6;
constexpr int kH   = 256;
constexpr int kG   = 4 * kH;    // 1024
constexpr int kTc  = 16;        // time chunk
constexpr int kMc  = kTc * kB;  // 16384 rows per chunk
}

// ---------------- zero-fill (states) ---------------------------------------
__global__ __launch_bounds__(256)
void zero_fill(float* __restrict__ p)
{
    p[blockIdx.x * 256 + threadIdx.x] = 0.f;
}

// ---------------- first layer: u1 = relu(x @ Wi1^T + bi1), K = 6 -----------
__global__ __launch_bounds__(256)
void in_mlp1(const float* __restrict__ x, const float* __restrict__ Wi1,
             const float* __restrict__ bi1, float* __restrict__ out)
{
    const int idx = blockIdx.x * 256 + threadIdx.x;   // over Mc*H
    const int col = idx & (kH - 1);
    const int row = idx >> 8;
    const float* xr = x + (size_t)row * kLag;
    const float* w  = Wi1 + col * kLag;
    float s = bi1[col];
#pragma unroll
    for (int k = 0; k < kLag; ++k) s = fmaf(xr[k], w[k], s);
    out[idx] = fmaxf(s, 0.f);
}

// ---------------- generic 64x64 tiled fp32 GEMM ----------------------------
// C[M,N] = act(A @ W^T + bias)
// A[M,K] = concat(A0[M,K0], A1[M,K-K0]) row-major; W[N,K] = concat(W0[N,WK0],
// W1[N,K-WK0]) row-major. K0/WK0 multiples of 16.
template<bool RELU_C, bool RELU_A, bool HAS_BIAS>
__global__ __launch_bounds__(256)
void gemm64(const float* __restrict__ A0, const float* __restrict__ A1, int K0,
            const float* __restrict__ W0, const float* __restrict__ W1, int WK0,
            int K, const float* __restrict__ bias,
            float* __restrict__ C, int N)
{
    // row stride 68 floats = 272 B = 16*17 -> every row 16B-aligned (b128 LDS
    // reads); write aliasing is 2-way only (free on gfx950).
    __shared__ float As[16][68];
    __shared__ float Ws[16][68];
    const int tid = threadIdx.x;
    const int m0 = blockIdx.y * 64;
    const int n0 = blockIdx.x * 64;
    const int lr = tid >> 2;          // 0..63 tile row to load
    const int lc = (tid & 3) << 2;    // 0,4,8,12 k-offset to load (float4)
    const int tm = (tid >> 4) << 2;   // micro-tile row base (4 rows)
    const int tn = (tid & 15) << 2;   // micro-tile col base (4 cols)

    float acc[4][4];
#pragma unroll
    for (int i = 0; i < 4; ++i)
#pragma unroll
        for (int j = 0; j < 4; ++j) acc[i][j] = 0.f;

    for (int kk = 0; kk < K; kk += 16) {
        const int k = kk + lc;
        float4 av, wv;
        if (k < K0) av = *(const float4*)(A0 + (size_t)(m0 + lr) * K0 + k);
        else        av = *(const float4*)(A1 + (size_t)(m0 + lr) * (K - K0) + (k - K0));
        if (RELU_A) {
            av.x = fmaxf(av.x, 0.f); av.y = fmaxf(av.y, 0.f);
            av.z = fmaxf(av.z, 0.f); av.w = fmaxf(av.w, 0.f);
        }
        if (k < WK0) wv = *(const float4*)(W0 + (size_t)(n0 + lr) * WK0 + k);
        else         wv = *(const float4*)(W1 + (size_t)(n0 + lr) * (K - WK0) + (k - WK0));
        As[lc + 0][lr] = av.x; As[lc + 1][lr] = av.y;
        As[lc + 2][lr] = av.z; As[lc + 3][lr] = av.w;
        Ws[lc + 0][lr] = wv.x; Ws[lc + 1][lr] = wv.y;
        Ws[lc + 2][lr] = wv.z; Ws[lc + 3][lr] = wv.w;
        __syncthreads();
#pragma unroll
        for (int k2 = 0; k2 < 16; ++k2) {
            float a[4], b[4];
#pragma unroll
            for (int i = 0; i < 4; ++i) a[i] = As[k2][tm + i];
#pragma unroll
            for (int j = 0; j < 4; ++j) b[j] = Ws[k2][tn + j];
#pragma unroll
            for (int i = 0; i < 4; ++i)
#pragma unroll
                for (int j = 0; j < 4; ++j)
                    acc[i][j] = fmaf(a[i], b[j], acc[i][j]);
        }
        __syncthreads();
    }

#pragma unroll
    for (int i = 0; i < 4; ++i) {
        float4 v;
        float* vp = &v.x;
#pragma unroll
        for (int j = 0; j < 4; ++j) {
            float cv = acc[i][j];
            if (HAS_BIAS) cv += bias[n0 + tn + j];
            if (RELU_C) cv = fmaxf(cv, 0.f);
            vp[j] = cv;
        }
        *(float4*)(C + (size_t)(m0 + tm + i) * N + n0 + tn) = v;
    }
}

// ---------------- LSTM cell (PyTorch gate order i,f,g,o) -------------------
__global__ __launch_bounds__(256)
void lstm_cell(const float* __restrict__ gates, const float* __restrict__ bih,
               const float* __restrict__ bhh, float* __restrict__ h,
               float* __restrict__ c, float* __restrict__ hs_out)
{
    const int idx = blockIdx.x * 256 + threadIdx.x;  // over B*H
    const int j = idx & (kH - 1);
    const int r = idx >> 8;
    const float* g = gates + (size_t)r * kG;
    const float gi = g[j]          + bih[j]          + bhh[j];
    const float gf = g[j + kH]     + bih[j + kH]     + bhh[j + kH];
    const float gg = g[j + 2*kH]   + bih[j + 2*kH]   + bhh[j + 2*kH];
    const float go = g[j + 3*kH]   + bih[j + 3*kH]   + bhh[j + 3*kH];
    const float si = 1.f / (1.f + expf(-gi));
    const float sf = 1.f / (1.f + expf(-gf));
    const float so = 1.f / (1.f + expf(-go));
    const float c2 = sf * c[idx] + si * tanhf(gg);
    const float h2 = so * tanhf(c2);
    c[idx] = c2;
    h[idx] = h2;
    if (hs_out) hs_out[idx] = h2;
}

// ---------------- last layer: y = y2 @ Wo3^T + bo3, N = 6 ------------------
__global__ __launch_bounds__(256)
void out_mlp3(const float* __restrict__ y2, const float* __restrict__ Wo3,
              const float* __restrict__ bo3, float* __restrict__ out)
{
    const int lane = threadIdx.x & 63;
    const int row  = blockIdx.x * 4 + (threadIdx.x >> 6);
    const float4 v = *(const float4*)(y2 + (size_t)row * kH + lane * 4);
    float s[kLag];
#pragma unroll
    for (int o = 0; o < kLag; ++o) {
        const float4 w = *(const float4*)(Wo3 + o * kH + lane * 4);
        s[o] = v.x * w.x + v.y * w.y + v.z * w.z + v.w * w.w;
    }
#pragma unroll
    for (int off = 32; off > 0; off >>= 1) {
#pragma unroll
        for (int o = 0; o < kLag; ++o) s[o] += __shfl_down(s[o], off);
    }
    if (lane == 0) {
#pragma unroll
        for (int o = 0; o < kLag; ++o)
            out[(size_t)row * kLag + o] = s[o] + bo3[o];
    }
}

// ---------------------------------------------------------------------------
extern "C" void kernel_launch(void* const* d_in, const int* in_sizes, int n_in,
                              void* d_out, int out_size, void* d_ws, size_t ws_size,
                              hipStream_t stream)
{
    const float* x    = (const float*)d_in[0];
    const float* Wi1  = (const float*)d_in[1];
    const float* bi1  = (const float*)d_in[2];
    const float* Wi2  = (const float*)d_in[3];
    const float* bi2  = (const float*)d_in[4];
    const float* Wi3  = (const float*)d_in[5];
    const float* bi3  = (const float*)d_in[6];
    const float* Wih0 = (const float*)d_in[7];
    const float* Whh0 = (const float*)d_in[8];
    const float* bih0 = (const float*)d_in[9];
    const float* bhh0 = (const float*)d_in[10];
    const float* Wih1 = (const float*)d_in[11];
    const float* Whh1 = (const float*)d_in[12];
    const float* bih1 = (const float*)d_in[13];
    const float* bhh1 = (const float*)d_in[14];
    const float* Wo1  = (const float*)d_in[15];
    const float* bo1  = (const float*)d_in[16];
    const float* Wo2  = (const float*)d_in[17];
    const float* bo2  = (const float*)d_in[18];
    const float* Wo3  = (const float*)d_in[19];
    const float* bo3  = (const float*)d_in[20];
    float* outp = (float*)d_out;

    // workspace layout (floats): s1,s2,Uc (Mc*H each) + h0,c0,h1,c1 (B*H) +
    // gbuf (B*4H)  => 14,680,064 floats = 56 MB
    float* ws   = (float*)d_ws;
    float* s1   = ws;
    float* s2   = s1 + (size_t)kMc * kH;
    float* Uc   = s2 + (size_t)kMc * kH;
    float* h0   = Uc + (size_t)kMc * kH;
    float* c0   = h0 + (size_t)kB * kH;
    float* h1   = c0 + (size_t)kB * kH;
    float* c1   = h1 + (size_t)kB * kH;
    float* gbuf = c1 + (size_t)kB * kH;

    // zero LSTM states (h0,c0,h1,c1 contiguous: 4*B*H floats)
    zero_fill<<<4 * kB * kH / 256, 256, 0, stream>>>(h0);

    for (int t0 = 0; t0 < kT; t0 += kTc) {
        // ---- input MLP for chunk: x -> s1 -> s2 -> Uc ----
        in_mlp1<<<kMc * kH / 256, 256, 0, stream>>>(
            x + (size_t)t0 * kB * kLag, Wi1, bi1, s1);
        gemm64<true, false, true><<<dim3(kH / 64, kMc / 64), 256, 0, stream>>>(
            s1, nullptr, kH, Wi2, nullptr, kH, kH, bi2, s2, kH);
        gemm64<true, false, true><<<dim3(kH / 64, kMc / 64), 256, 0, stream>>>(
            s2, nullptr, kH, Wi3, nullptr, kH, kH, bi3, Uc, kH);

        // ---- LSTM steps; hs_t overwrites u_t in Uc ----
        for (int tt = 0; tt < kTc; ++tt) {
            float* ut = Uc + (size_t)tt * kB * kH;
            gemm64<false, false, false><<<dim3(kG / 64, kB / 64), 256, 0, stream>>>(
                ut, h0, kH, Wih0, Whh0, kH, 2 * kH, nullptr, gbuf, kG);
            lstm_cell<<<kB * kH / 256, 256, 0, stream>>>(
                gbuf, bih0, bhh0, h0, c0, nullptr);
            gemm64<false, false, false><<<dim3(kG / 64, kB / 64), 256, 0, stream>>>(
                h0, h1, kH, Wih1, Whh1, kH, 2 * kH, nullptr, gbuf, kG);
            lstm_cell<<<kB * kH / 256, 256, 0, stream>>>(
                gbuf, bih1, bhh1, h1, c1, ut);
        }

        // ---- output MLP for chunk: Uc(hs) -> s1 -> s2 -> out ----
        gemm64<true, true, true><<<dim3(kH / 64, kMc / 64), 256, 0, stream>>>(
            Uc, nullptr, kH, Wo1, nullptr, kH, kH, bo1, s1, kH);
        gemm64<true, false, true><<<dim3(kH / 64, kMc / 64), 256, 0, stream>>>(
            s1, nullptr, kH, Wo2, nullptr, kH, kH, bo2, s2, kH);
        out_mlp3<<<kMc / 4, 256, 0, stream>>>(
            s2, Wo3, bo3, outp + (size_t)t0 * kB * kLag);
    }
}